// Round 1
// baseline (2252.718 us; speedup 1.0000x reference)
//
#include <hip/hip_runtime.h>

#define D_IN 256

// ---------------------------------------------------------------------------
// CSR build: histogram -> single-block exclusive scan -> scatter
// ---------------------------------------------------------------------------
__global__ void hist_kernel(const int* __restrict__ dst, int* __restrict__ hist, int E) {
    int i = blockIdx.x * blockDim.x + threadIdx.x;
    if (i < E) atomicAdd(&hist[dst[i]], 1);
}

// hist may alias cursor: each thread only touches its own chunk, and reads
// hist[i] before writing cursor[i].
__global__ __launch_bounds__(1024) void scan_kernel(const int* __restrict__ hist,
                                                    int* __restrict__ row_ptr,
                                                    int* __restrict__ cursor, int N) {
    __shared__ int partial[1024];
    int tid = threadIdx.x;
    int chunk = (N + 1023) >> 10;
    int beg = tid * chunk;
    int end = min(beg + chunk, N);
    int s = 0;
    for (int i = beg; i < end; ++i) s += hist[i];
    partial[tid] = s;
    __syncthreads();
    for (int off = 1; off < 1024; off <<= 1) {
        int v = (tid >= off) ? partial[tid - off] : 0;
        __syncthreads();
        partial[tid] += v;
        __syncthreads();
    }
    int run = (tid == 0) ? 0 : partial[tid - 1];
    for (int i = beg; i < end; ++i) {
        int h = hist[i];            // read before aliased write
        row_ptr[i] = run;
        cursor[i] = run;
        run += h;
    }
    if (tid == 1023) row_ptr[N] = partial[1023];
}

__global__ void scatter_kernel(const int* __restrict__ src, const int* __restrict__ dst,
                               const float* __restrict__ w, int* __restrict__ cursor,
                               int* __restrict__ csr_src, float* __restrict__ csr_w, int E) {
    int i = blockIdx.x * blockDim.x + threadIdx.x;
    if (i < E) {
        int d = dst[i];
        int pos = atomicAdd(&cursor[d], 1);
        csr_src[pos] = src[i];
        csr_w[pos] = w[i];
    }
}

// ---------------------------------------------------------------------------
// GEMM: C[M,NC] = A[M,K] @ W[K,NC]; block = 256 thr, 64 rows/block, K-tile 32
// ---------------------------------------------------------------------------
template <int NC>
__global__ __launch_bounds__(256) void gemm_kernel(const float* __restrict__ A,
                                                   const float* __restrict__ Wm,
                                                   float* __restrict__ C, int M, int K) {
    constexpr int NJ = NC / 4;
    __shared__ float As[64][33];
    __shared__ float Ws[32][NC];
    int tid = threadIdx.x;
    int row = tid & 63;
    int cg  = tid >> 6;            // 0..3
    int row0 = blockIdx.x * 64;

    float acc[NJ];
#pragma unroll
    for (int j = 0; j < NJ; ++j) acc[j] = 0.f;

    for (int k0 = 0; k0 < K; k0 += 32) {
#pragma unroll
        for (int i = 0; i < 8; ++i) {               // 64x32 A tile
            int lin = tid + 256 * i;
            int r = lin >> 5, k = lin & 31;
            As[r][k] = (row0 + r < M) ? A[(size_t)(row0 + r) * K + k0 + k] : 0.f;
        }
        constexpr int WL = (32 * NC + 255) / 256;   // 32xNC W tile
#pragma unroll
        for (int i = 0; i < WL; ++i) {
            int lin = tid + 256 * i;
            if (lin < 32 * NC) {
                int kk = lin / NC, c = lin % NC;
                Ws[kk][c] = Wm[(size_t)(k0 + kk) * NC + c];
            }
        }
        __syncthreads();
#pragma unroll 8
        for (int kk = 0; kk < 32; ++kk) {
            float a = As[row][kk];
#pragma unroll
            for (int j = 0; j < NJ; ++j) acc[j] += a * Ws[kk][cg + 4 * j];
        }
        __syncthreads();
    }
    if (row0 + row < M) {
#pragma unroll
        for (int j = 0; j < NJ; ++j) C[(size_t)(row0 + row) * NC + cg + 4 * j] = acc[j];
    }
}

// ---------------------------------------------------------------------------
// Aggregation: zout[n,d] (+)= leaky_relu(sum_e w_e * support[src_e, d]) / 3
// ---------------------------------------------------------------------------
template <int D>
__global__ void agg_kernel(const float* __restrict__ support, const int* __restrict__ row_ptr,
                           const int* __restrict__ csr_src, const float* __restrict__ csr_w,
                           float* __restrict__ zout, int N, int first) {
    int t = blockIdx.x * blockDim.x + threadIdx.x;
    if (t >= N * D) return;
    int n = t / D;
    int d = t - n * D;
    int beg = row_ptr[n], end = row_ptr[n + 1];
    float acc = 0.f;
    for (int e = beg; e < end; ++e) {
        int s = csr_src[e];
        float w = csr_w[e];
        acc += w * support[(size_t)s * D + d];
    }
    float v = (acc >= 0.f) ? acc : 0.2f * acc;   // leaky_relu(0.2)
    v *= (1.f / 3.f);
    if (first) zout[t] = v;
    else       zout[t] += v;
}

// ---------------------------------------------------------------------------
// Student-t soft assignment (V = 1): q = 1/(1+dist), row-normalized
// ---------------------------------------------------------------------------
__global__ void q_kernel(const float* __restrict__ z, const float* __restrict__ cl,
                         float* __restrict__ qout, int N) {
    __shared__ float c[200];
    if (threadIdx.x < 200) c[threadIdx.x] = cl[threadIdx.x];
    __syncthreads();
    int n = blockIdx.x * blockDim.x + threadIdx.x;
    if (n >= N) return;
    float zr[20];
#pragma unroll
    for (int d = 0; d < 20; ++d) zr[d] = z[(size_t)n * 20 + d];
    float qs[10];
    float sum = 0.f;
#pragma unroll
    for (int k = 0; k < 10; ++k) {
        float dist = 0.f;
#pragma unroll
        for (int d = 0; d < 20; ++d) {
            float t = zr[d] - c[k * 20 + d];
            dist += t * t;
        }
        float qk = 1.0f / (1.0f + dist);
        qs[k] = qk;
        sum += qk;
    }
    float inv = 1.0f / sum;
#pragma unroll
    for (int k = 0; k < 10; ++k) qout[(size_t)n * 10 + k] = qs[k] * inv;
}

// ---------------------------------------------------------------------------
extern "C" void kernel_launch(void* const* d_in, const int* in_sizes, int n_in,
                              void* d_out, int out_size, void* d_ws, size_t ws_size,
                              hipStream_t stream) {
    const float* feat[3] = {(const float*)d_in[0], (const float*)d_in[1], (const float*)d_in[2]};
    const int*   srcs[3] = {(const int*)d_in[3], (const int*)d_in[6], (const int*)d_in[9]};
    const int*   dsts[3] = {(const int*)d_in[4], (const int*)d_in[7], (const int*)d_in[10]};
    const float* ews[3]  = {(const float*)d_in[5], (const float*)d_in[8], (const float*)d_in[11]};
    const float* Wp[3][3];
    for (int b = 0; b < 3; ++b)
        for (int l = 0; l < 3; ++l)
            Wp[b][l] = (const float*)d_in[12 + 3 * b + l];
    const float* cluster = (const float*)d_in[21];

    const int N = in_sizes[0] / D_IN;   // 50000
    const int E = in_sizes[3];          // 800000

    // ---- workspace layout (all rewritten every call) ----
    size_t off = 0;
    auto take = [&](size_t bytes) -> void* {
        void* p = (char*)d_ws + off;
        off += (bytes + 255) & ~(size_t)255;
        return p;
    };
    int*   cursor  = (int*)take((size_t)3 * N * 4);         // also the histogram
    int*   rowptr  = (int*)take((size_t)3 * (N + 1) * 4);
    int*   csrsrc  = (int*)take((size_t)3 * E * 4);
    float* csrw    = (float*)take((size_t)3 * E * 4);
    float* support = (float*)take((size_t)N * 128 * 4);
    float* z1      = (float*)take((size_t)N * 128 * 4);
    float* z2      = (float*)take((size_t)N * 64 * 4);
    (void)ws_size;

    float* zout = (float*)d_out;                 // [N,20]
    float* qout = zout + (size_t)N * 20;         // [N,10]

    // ---- CSR build for the 3 graphs ----
    hipMemsetAsync(cursor, 0, (size_t)3 * N * 4, stream);
    int gE = (E + 255) / 256;
    for (int g = 0; g < 3; ++g) {
        hist_kernel<<<gE, 256, 0, stream>>>(dsts[g], cursor + (size_t)g * N, E);
        scan_kernel<<<1, 1024, 0, stream>>>(cursor + (size_t)g * N,
                                            rowptr + (size_t)g * (N + 1),
                                            cursor + (size_t)g * N, N);
        scatter_kernel<<<gE, 256, 0, stream>>>(srcs[g], dsts[g], ews[g],
                                               cursor + (size_t)g * N,
                                               csrsrc + (size_t)g * E,
                                               csrw + (size_t)g * E, E);
    }

    int gM = (N + 63) / 64;
    // ---- layer 1: [N,256]@[256,128] -> agg(D=128) -> z1 ----
    for (int b = 0; b < 3; ++b) {
        gemm_kernel<128><<<gM, 256, 0, stream>>>(feat[b], Wp[b][0], support, N, 256);
        agg_kernel<128><<<(N * 128 + 255) / 256, 256, 0, stream>>>(
            support, rowptr + (size_t)b * (N + 1), csrsrc + (size_t)b * E,
            csrw + (size_t)b * E, z1, N, b == 0);
    }
    // ---- layer 2: [N,128]@[128,64] -> agg(D=64) -> z2 ----
    for (int b = 0; b < 3; ++b) {
        gemm_kernel<64><<<gM, 256, 0, stream>>>(z1, Wp[b][1], support, N, 128);
        agg_kernel<64><<<(N * 64 + 255) / 256, 256, 0, stream>>>(
            support, rowptr + (size_t)b * (N + 1), csrsrc + (size_t)b * E,
            csrw + (size_t)b * E, z2, N, b == 0);
    }
    // ---- layer 3: [N,64]@[64,20] -> agg(D=20) -> z (d_out) ----
    for (int b = 0; b < 3; ++b) {
        gemm_kernel<20><<<gM, 256, 0, stream>>>(z2, Wp[b][2], support, N, 64);
        agg_kernel<20><<<(N * 20 + 255) / 256, 256, 0, stream>>>(
            support, rowptr + (size_t)b * (N + 1), csrsrc + (size_t)b * E,
            csrw + (size_t)b * E, zout, N, b == 0);
    }
    // ---- student-t q ----
    q_kernel<<<(N + 255) / 256, 256, 0, stream>>>(zout, cluster, qout, N);
}

// Round 2
// 957.694 us; speedup vs baseline: 2.3522x; 2.3522x over previous
//
#include <hip/hip_runtime.h>

#define D_IN 256

typedef __bf16 bf16x8 __attribute__((ext_vector_type(8)));
typedef float f32x4 __attribute__((ext_vector_type(4)));

static __device__ __forceinline__ ushort f2b(float f) {
    uint u = __float_as_uint(f);
    u += 0x7FFF + ((u >> 16) & 1);          // round-to-nearest-even
    return (ushort)(u >> 16);
}
static __device__ __forceinline__ float b2f(ushort h) {
    return __uint_as_float(((uint)h) << 16);
}
static __device__ __forceinline__ float lrelu(float v) {
    return (v >= 0.f) ? v : 0.2f * v;
}

// ---------------------------------------------------------------------------
// CSR build: histogram -> per-graph single-block scan -> scatter
// ---------------------------------------------------------------------------
__global__ void hist3_kernel(const int* __restrict__ d0, const int* __restrict__ d1,
                             const int* __restrict__ d2, int* __restrict__ hist,
                             int E, int N) {
    int g = blockIdx.y;
    const int* d = (g == 0) ? d0 : (g == 1) ? d1 : d2;
    int i = blockIdx.x * blockDim.x + threadIdx.x;
    if (i < E) atomicAdd(&hist[g * N + d[i]], 1);
}

// hist aliases cursor: each thread reads hist[i] before writing cursor[i].
__global__ __launch_bounds__(1024) void scan3_kernel(int* __restrict__ hist,
                                                     int* __restrict__ row_ptr,
                                                     int N) {
    int g = blockIdx.x;
    int* h = hist + g * N;                 // also the cursor output
    int* rp = row_ptr + g * (N + 1);
    __shared__ int partial[1024];
    int tid = threadIdx.x;
    int chunk = (N + 1023) >> 10;
    int beg = tid * chunk;
    int end = min(beg + chunk, N);
    int s = 0;
    for (int i = beg; i < end; ++i) s += h[i];
    partial[tid] = s;
    __syncthreads();
    for (int off = 1; off < 1024; off <<= 1) {
        int v = (tid >= off) ? partial[tid - off] : 0;
        __syncthreads();
        partial[tid] += v;
        __syncthreads();
    }
    int run = (tid == 0) ? 0 : partial[tid - 1];
    for (int i = beg; i < end; ++i) {
        int hv = h[i];                     // read before aliased write
        rp[i] = run;
        h[i] = run;                        // cursor
        run += hv;
    }
    if (tid == 1023) rp[N] = partial[1023];
}

__global__ void scatter3_kernel(const int* __restrict__ s0, const int* __restrict__ s1,
                                const int* __restrict__ s2, const int* __restrict__ d0,
                                const int* __restrict__ d1, const int* __restrict__ d2,
                                const float* __restrict__ w0, const float* __restrict__ w1,
                                const float* __restrict__ w2, int* __restrict__ cursor,
                                int* __restrict__ csr_src, float* __restrict__ csr_w,
                                int E, int N) {
    int g = blockIdx.y;
    const int* src = (g == 0) ? s0 : (g == 1) ? s1 : s2;
    const int* dst = (g == 0) ? d0 : (g == 1) ? d1 : d2;
    const float* w = (g == 0) ? w0 : (g == 1) ? w1 : w2;
    int i = blockIdx.x * blockDim.x + threadIdx.x;
    if (i < E) {
        int d = dst[i];
        int pos = atomicAdd(&cursor[g * N + d], 1);
        csr_src[(size_t)g * E + pos] = src[i];
        csr_w[(size_t)g * E + pos] = w[i];
    }
}

// ---------------------------------------------------------------------------
// Weight prep: W[K][NC] fp32 -> Wt[NCP][K] bf16 (transposed, col-padded zeros)
// ---------------------------------------------------------------------------
template <int K, int NC, int NCP>
__global__ void prep_kernel(const float* __restrict__ W0, const float* __restrict__ W1,
                            const float* __restrict__ W2, ushort* __restrict__ Wt) {
    int g = blockIdx.y;
    const float* W = (g == 0) ? W0 : (g == 1) ? W1 : W2;
    ushort* o = Wt + (size_t)g * NCP * K;
    for (int idx = blockIdx.x * 256 + threadIdx.x; idx < NCP * K; idx += gridDim.x * 256) {
        int c = idx / K, k = idx - c * K;
        float v = (c < NC) ? W[(size_t)k * NC + c] : 0.f;
        o[idx] = f2b(v);
    }
}

// ---------------------------------------------------------------------------
// MFMA bf16 GEMM: C[M,NCP] = bf16(A[M,K]) @ Wt^T ; C stored bf16
// Block: 256 thr = 4 waves, tile BM=128 x BN=NCP, BK=32.
// mfma_f32_16x16x32_bf16 layouts:
//   A frag: row = lane&15, k = 8*(lane>>4)+j
//   B frag: col = lane&15, k = 8*(lane>>4)+j   (Bs holds W^T: Bs[c][k])
//   D frag: col = lane&15, row = 4*(lane>>4)+r
// LDS rows padded to 40 ushorts (80B) -> 2-way bank alias only (free).
// ---------------------------------------------------------------------------
template <int K, int NCP>
__global__ __launch_bounds__(256) void gemm_kernel(const float* __restrict__ A,
                                                   const ushort* __restrict__ Wt,
                                                   ushort* __restrict__ C, int M) {
    constexpr int WAVES_N = (NCP >= 128) ? 2 : 1;
    constexpr int WAVES_M = 4 / WAVES_N;
    constexpr int WM = 128 / WAVES_M;      // 64 or 32
    constexpr int WN = NCP / WAVES_N;      // 64 or 32
    constexpr int FM = WM / 16;
    constexpr int FN = WN / 16;

    __shared__ ushort As[128 * 40];
    __shared__ ushort Bs[NCP * 40];

    int tid = threadIdx.x;
    int lane = tid & 63;
    int wave = tid >> 6;
    int lo = lane & 15, hi = lane >> 4;
    int wm0, wn0;
    if (WAVES_N == 2) { wm0 = (wave >> 1) * WM; wn0 = (wave & 1) * WN; }
    else              { wm0 = wave * WM;        wn0 = 0; }
    int row0 = blockIdx.x * 128;

    f32x4 acc[FM][FN];
#pragma unroll
    for (int i = 0; i < FM; ++i)
#pragma unroll
        for (int j = 0; j < FN; ++j) acc[i][j] = (f32x4){0.f, 0.f, 0.f, 0.f};

    for (int k0 = 0; k0 < K; k0 += 32) {
        __syncthreads();
        // stage A tile 128x32 (fp32 -> bf16)
#pragma unroll
        for (int i = 0; i < 4; ++i) {
            int f = tid + 256 * i;
            int r = f >> 3, kc = f & 7;
            float4 v = make_float4(0.f, 0.f, 0.f, 0.f);
            if (row0 + r < M)
                v = *(const float4*)&A[(size_t)(row0 + r) * K + k0 + kc * 4];
            ushort4 u;
            u.x = f2b(v.x); u.y = f2b(v.y); u.z = f2b(v.z); u.w = f2b(v.w);
            *(ushort4*)&As[r * 40 + kc * 4] = u;
        }
        // stage B tile NCPx32 from Wt (bf16 copy)
        for (int idx = tid; idx < NCP * 4; idx += 256) {
            int c = idx >> 2, q = idx & 3;
            *(uint4*)&Bs[c * 40 + q * 8] = *(const uint4*)&Wt[(size_t)c * K + k0 + q * 8];
        }
        __syncthreads();

        bf16x8 afr[FM], bfr[FN];
#pragma unroll
        for (int fm = 0; fm < FM; ++fm)
            afr[fm] = *(const bf16x8*)&As[(wm0 + fm * 16 + lo) * 40 + 8 * hi];
#pragma unroll
        for (int fn = 0; fn < FN; ++fn)
            bfr[fn] = *(const bf16x8*)&Bs[(wn0 + fn * 16 + lo) * 40 + 8 * hi];
#pragma unroll
        for (int fm = 0; fm < FM; ++fm)
#pragma unroll
            for (int fn = 0; fn < FN; ++fn)
                acc[fm][fn] = __builtin_amdgcn_mfma_f32_16x16x32_bf16(
                    afr[fm], bfr[fn], acc[fm][fn], 0, 0, 0);
    }

#pragma unroll
    for (int fm = 0; fm < FM; ++fm)
#pragma unroll
        for (int fn = 0; fn < FN; ++fn)
#pragma unroll
            for (int r = 0; r < 4; ++r) {
                int row = row0 + wm0 + fm * 16 + hi * 4 + r;
                if (row < M)
                    C[(size_t)row * NCP + wn0 + fn * 16 + lo] = f2b(acc[fm][fn][r]);
            }
}

// ---------------------------------------------------------------------------
// Fused 3-branch aggregation:
//   z[n,:] = sum_g lrelu(sum_e w_e * sup_g[src_e,:]) / 3
// LPN lanes per node, 4 features (one ushort4 = 4 bf16) per lane.
// ---------------------------------------------------------------------------
template <int DS, int LPN, bool OUT20>
__global__ __launch_bounds__(256) void agg3_kernel(const ushort* __restrict__ sup,
                                                   const int* __restrict__ rowptr,
                                                   const int* __restrict__ csrsrc,
                                                   const float* __restrict__ csrw,
                                                   float* __restrict__ z, int N, int E) {
    int t = blockIdx.x * 256 + threadIdx.x;
    int n = t / LPN;
    int sub = t - n * LPN;
    if (n >= N) return;
    float t0 = 0.f, t1 = 0.f, t2 = 0.f, t3 = 0.f;
#pragma unroll
    for (int g = 0; g < 3; ++g) {
        const int* rp = rowptr + g * (N + 1);
        const int* cs = csrsrc + (size_t)g * E;
        const float* cw = csrw + (size_t)g * E;
        const ushort* sg = sup + (size_t)g * N * DS;
        int beg = rp[n], end = rp[n + 1];
        float a0 = 0.f, a1 = 0.f, a2 = 0.f, a3 = 0.f;
        for (int e = beg; e < end; ++e) {
            int s = cs[e];
            float w = cw[e];
            ushort4 v = *(const ushort4*)&sg[(size_t)s * DS + sub * 4];
            a0 += w * b2f(v.x);
            a1 += w * b2f(v.y);
            a2 += w * b2f(v.z);
            a3 += w * b2f(v.w);
        }
        t0 += lrelu(a0); t1 += lrelu(a1); t2 += lrelu(a2); t3 += lrelu(a3);
    }
    const float s3 = 1.f / 3.f;
    if (OUT20) {
        if (sub < 5) {
            float4 o = make_float4(t0 * s3, t1 * s3, t2 * s3, t3 * s3);
            *(float4*)&z[(size_t)n * 20 + sub * 4] = o;   // 80B rows: 16B-aligned
        }
    } else {
        float4 o = make_float4(t0 * s3, t1 * s3, t2 * s3, t3 * s3);
        *(float4*)&z[(size_t)n * DS + sub * 4] = o;
    }
}

// ---------------------------------------------------------------------------
// Student-t soft assignment (V = 1): q = 1/(1+dist), row-normalized
// ---------------------------------------------------------------------------
__global__ void q_kernel(const float* __restrict__ z, const float* __restrict__ cl,
                         float* __restrict__ qout, int N) {
    __shared__ float c[200];
    if (threadIdx.x < 200) c[threadIdx.x] = cl[threadIdx.x];
    __syncthreads();
    int n = blockIdx.x * blockDim.x + threadIdx.x;
    if (n >= N) return;
    float zr[20];
#pragma unroll
    for (int d = 0; d < 20; ++d) zr[d] = z[(size_t)n * 20 + d];
    float qs[10];
    float sum = 0.f;
#pragma unroll
    for (int k = 0; k < 10; ++k) {
        float dist = 0.f;
#pragma unroll
        for (int d = 0; d < 20; ++d) {
            float t = zr[d] - c[k * 20 + d];
            dist += t * t;
        }
        float qk = 1.0f / (1.0f + dist);
        qs[k] = qk;
        sum += qk;
    }
    float inv = 1.0f / sum;
#pragma unroll
    for (int k = 0; k < 10; ++k) qout[(size_t)n * 10 + k] = qs[k] * inv;
}

// ---------------------------------------------------------------------------
extern "C" void kernel_launch(void* const* d_in, const int* in_sizes, int n_in,
                              void* d_out, int out_size, void* d_ws, size_t ws_size,
                              hipStream_t stream) {
    const float* feat[3] = {(const float*)d_in[0], (const float*)d_in[1], (const float*)d_in[2]};
    const int*   srcs[3] = {(const int*)d_in[3], (const int*)d_in[6], (const int*)d_in[9]};
    const int*   dsts[3] = {(const int*)d_in[4], (const int*)d_in[7], (const int*)d_in[10]};
    const float* ews[3]  = {(const float*)d_in[5], (const float*)d_in[8], (const float*)d_in[11]};
    const float* Wp[3][3];
    for (int b = 0; b < 3; ++b)
        for (int l = 0; l < 3; ++l)
            Wp[b][l] = (const float*)d_in[12 + 3 * b + l];
    const float* cluster = (const float*)d_in[21];

    const int N = in_sizes[0] / D_IN;   // 50000
    const int E = in_sizes[3];          // 800000

    // ---- workspace layout ----
    size_t off = 0;
    auto take = [&](size_t bytes) -> void* {
        void* p = (char*)d_ws + off;
        off += (bytes + 255) & ~(size_t)255;
        return p;
    };
    int*    cursor = (int*)take((size_t)3 * N * 4);          // hist -> cursor
    int*    rowptr = (int*)take((size_t)3 * (N + 1) * 4);
    int*    csrsrc = (int*)take((size_t)3 * E * 4);
    float*  csrw   = (float*)take((size_t)3 * E * 4);
    ushort* wt1    = (ushort*)take((size_t)3 * 128 * 256 * 2);
    ushort* wt2    = (ushort*)take((size_t)3 * 64 * 128 * 2);
    ushort* wt3    = (ushort*)take((size_t)3 * 32 * 64 * 2);
    ushort* sup    = (ushort*)take((size_t)3 * N * 128 * 2);  // reused per layer
    float*  z1     = (float*)take((size_t)N * 128 * 4);
    float*  z2     = (float*)take((size_t)N * 64 * 4);
    (void)ws_size;

    float* zout = (float*)d_out;                 // [N,20] fp32
    float* qout = zout + (size_t)N * 20;         // [N,10]

    // ---- CSR build ----
    hipMemsetAsync(cursor, 0, (size_t)3 * N * 4, stream);
    int gE = (E + 255) / 256;
    hist3_kernel<<<dim3(gE, 3), 256, 0, stream>>>(dsts[0], dsts[1], dsts[2], cursor, E, N);
    scan3_kernel<<<3, 1024, 0, stream>>>(cursor, rowptr, N);
    scatter3_kernel<<<dim3(gE, 3), 256, 0, stream>>>(srcs[0], srcs[1], srcs[2],
                                                     dsts[0], dsts[1], dsts[2],
                                                     ews[0], ews[1], ews[2],
                                                     cursor, csrsrc, csrw, E, N);

    // ---- weight prep (fp32 -> transposed bf16) ----
    prep_kernel<256, 128, 128><<<dim3(32, 3), 256, 0, stream>>>(Wp[0][0], Wp[1][0], Wp[2][0], wt1);
    prep_kernel<128, 64, 64><<<dim3(16, 3), 256, 0, stream>>>(Wp[0][1], Wp[1][1], Wp[2][1], wt2);
    prep_kernel<64, 20, 32><<<dim3(8, 3), 256, 0, stream>>>(Wp[0][2], Wp[1][2], Wp[2][2], wt3);

    int gM = (N + 127) / 128;   // 391

    // ---- layer 1: [N,256]@[256,128] x3 -> fused agg(D=128) -> z1 ----
    for (int b = 0; b < 3; ++b)
        gemm_kernel<256, 128><<<gM, 256, 0, stream>>>(feat[b], wt1 + (size_t)b * 128 * 256,
                                                      sup + (size_t)b * N * 128, N);
    agg3_kernel<128, 32, false><<<(N * 32 + 255) / 256, 256, 0, stream>>>(
        sup, rowptr, csrsrc, csrw, z1, N, E);

    // ---- layer 2: [N,128]@[128,64] x3 -> fused agg(D=64) -> z2 ----
    for (int b = 0; b < 3; ++b)
        gemm_kernel<128, 64><<<gM, 256, 0, stream>>>(z1, wt2 + (size_t)b * 64 * 128,
                                                     sup + (size_t)b * N * 64, N);
    agg3_kernel<64, 16, false><<<(N * 16 + 255) / 256, 256, 0, stream>>>(
        sup, rowptr, csrsrc, csrw, z2, N, E);

    // ---- layer 3: [N,64]@[64,20->32] x3 -> fused agg -> zout fp32 ----
    for (int b = 0; b < 3; ++b)
        gemm_kernel<64, 32><<<gM, 256, 0, stream>>>(z2, wt3 + (size_t)b * 32 * 64,
                                                    sup + (size_t)b * N * 32, N);
    agg3_kernel<32, 8, true><<<(N * 8 + 255) / 256, 256, 0, stream>>>(
        sup, rowptr, csrsrc, csrw, zout, N, E);

    // ---- student-t q ----
    q_kernel<<<(N + 255) / 256, 256, 0, stream>>>(zout, cluster, qout, N);
}

// Round 6
// 841.006 us; speedup vs baseline: 2.6786x; 1.1387x over previous
//
#include <hip/hip_runtime.h>

#define D_IN 256

typedef __bf16 bf16x8 __attribute__((ext_vector_type(8)));
typedef float f32x4 __attribute__((ext_vector_type(4)));

static __device__ __forceinline__ ushort f2b(float f) {
    uint u = __float_as_uint(f);
    u += 0x7FFF + ((u >> 16) & 1);          // round-to-nearest-even
    return (ushort)(u >> 16);
}
static __device__ __forceinline__ float blo(uint u) {  // low bf16 of a uint
    return __uint_as_float(u << 16);
}
static __device__ __forceinline__ float bhi(uint u) {  // high bf16 of a uint
    return __uint_as_float(u & 0xffff0000u);
}
static __device__ __forceinline__ float lrelu(float v) {
    return (v >= 0.f) ? v : 0.2f * v;
}

// ---------------------------------------------------------------------------
// CSR build: histogram -> per-graph single-block scan -> scatter (int2 records)
// ---------------------------------------------------------------------------
__global__ void hist3_kernel(const int* __restrict__ d0, const int* __restrict__ d1,
                             const int* __restrict__ d2, int* __restrict__ hist,
                             int E, int N) {
    int g = blockIdx.y;
    const int* d = (g == 0) ? d0 : (g == 1) ? d1 : d2;
    int i = blockIdx.x * blockDim.x + threadIdx.x;
    if (i < E) atomicAdd(&hist[g * N + d[i]], 1);
}

// hist aliases cursor: each thread reads hist[i] before writing cursor[i].
__global__ __launch_bounds__(1024) void scan3_kernel(int* __restrict__ hist,
                                                     int* __restrict__ row_ptr,
                                                     int N) {
    int g = blockIdx.x;
    int* h = hist + g * N;                 // becomes the cursor
    int* rp = row_ptr + g * (N + 1);
    __shared__ int partial[1024];
    int tid = threadIdx.x;
    int chunk = (N + 1023) >> 10;
    int beg = tid * chunk;
    int end = min(beg + chunk, N);
    int s = 0;
    for (int i = beg; i < end; ++i) s += h[i];
    partial[tid] = s;
    __syncthreads();
    for (int off = 1; off < 1024; off <<= 1) {
        int v = (tid >= off) ? partial[tid - off] : 0;
        __syncthreads();
        partial[tid] += v;
        __syncthreads();
    }
    int run = (tid == 0) ? 0 : partial[tid - 1];
    for (int i = beg; i < end; ++i) {
        int hv = h[i];                     // read before aliased write
        rp[i] = run;
        h[i] = run;                        // cursor
        run += hv;
    }
    if (tid == 1023) rp[N] = partial[1023];
}

__global__ void scatter3_kernel(const int* __restrict__ s0, const int* __restrict__ s1,
                                const int* __restrict__ s2, const int* __restrict__ d0,
                                const int* __restrict__ d1, const int* __restrict__ d2,
                                const float* __restrict__ w0, const float* __restrict__ w1,
                                const float* __restrict__ w2, int* __restrict__ cursor,
                                int2* __restrict__ csre, int E, int N) {
    int g = blockIdx.y;
    const int* src = (g == 0) ? s0 : (g == 1) ? s1 : s2;
    const int* dst = (g == 0) ? d0 : (g == 1) ? d1 : d2;
    const float* w = (g == 0) ? w0 : (g == 1) ? w1 : w2;
    int i = blockIdx.x * blockDim.x + threadIdx.x;
    if (i < E) {
        int d = dst[i];
        int pos = atomicAdd(&cursor[g * N + d], 1);
        unsigned long long rec = ((unsigned long long)(uint)__float_as_int(w[i]) << 32)
                               | (uint)src[i];
        __builtin_nontemporal_store(rec, (unsigned long long*)&csre[(size_t)g * E + pos]);
    }
}

// ---------------------------------------------------------------------------
// Weight prep: W_g[K][NC] fp32 -> Wt[3*NCP_PER][K] bf16 (transposed, padded)
// ---------------------------------------------------------------------------
template <int K, int NC, int NCP_PER>
__global__ void prep_kernel(const float* __restrict__ W0, const float* __restrict__ W1,
                            const float* __restrict__ W2, ushort* __restrict__ Wt) {
    int idx = blockIdx.x * 256 + threadIdx.x;
    if (idx >= 3 * NCP_PER * K) return;
    int row = idx / K, k = idx - row * K;
    int g = row / NCP_PER, cc = row - g * NCP_PER;
    const float* W = (g == 0) ? W0 : (g == 1) ? W1 : W2;
    Wt[idx] = f2b(cc < NC ? W[(size_t)k * NC + cc] : 0.f);
}

// ---------------------------------------------------------------------------
// MFMA bf16 GEMM: C[M,NCP] = bf16(A[M,K]) @ Wt^T ; C stored bf16.
// 256 thr = 4 waves (2x2), tile 128 x NCP, BK=32. B3: blockIdx.y = branch.
// mfma_f32_16x16x32_bf16: A row=lane&15,k=8*(lane>>4)+j ; B col=lane&15 same k;
// D col=lane&15, row=4*(lane>>4)+r.  LDS rows padded to 40 ushorts (80B).
// ---------------------------------------------------------------------------
template <int K, int NCP, bool B3>
__global__ __launch_bounds__(256) void gemm_kernel(const float* __restrict__ A0,
                                                   const float* __restrict__ A1,
                                                   const float* __restrict__ A2,
                                                   const ushort* __restrict__ Wt,
                                                   ushort* __restrict__ C, int M) {
    constexpr int FM = 4;             // WM = 64
    constexpr int FN = NCP / 32;      // WN = NCP/2
    const float* A = A0;
    const ushort* Wtg = Wt;
    ushort* Cg = C;
    if (B3) {
        int g = blockIdx.y;
        A = (g == 0) ? A0 : (g == 1) ? A1 : A2;
        Wtg = Wt + (size_t)g * NCP * K;
        Cg = C + (size_t)g * (size_t)M * NCP;
    }

    __shared__ ushort As[128 * 40];
    __shared__ ushort Bs[NCP * 40];

    int tid = threadIdx.x;
    int lane = tid & 63;
    int wave = tid >> 6;
    int lo = lane & 15, hi = lane >> 4;
    int wm0 = (wave >> 1) * 64;
    int wn0 = (wave & 1) * (NCP / 2);
    int row0 = blockIdx.x * 128;

    f32x4 acc[FM][FN];
#pragma unroll
    for (int i = 0; i < FM; ++i)
#pragma unroll
        for (int j = 0; j < FN; ++j) acc[i][j] = (f32x4){0.f, 0.f, 0.f, 0.f};

    for (int k0 = 0; k0 < K; k0 += 32) {
        __syncthreads();
#pragma unroll
        for (int i = 0; i < 4; ++i) {               // A tile 128x32 fp32->bf16
            int f = tid + 256 * i;
            int r = f >> 3, kc = f & 7;
            float4 v = make_float4(0.f, 0.f, 0.f, 0.f);
            if (row0 + r < M)
                v = *(const float4*)&A[(size_t)(row0 + r) * K + k0 + kc * 4];
            ushort4 u;
            u.x = f2b(v.x); u.y = f2b(v.y); u.z = f2b(v.z); u.w = f2b(v.w);
            *(ushort4*)&As[r * 40 + kc * 4] = u;
        }
        for (int idx = tid; idx < NCP * 4; idx += 256) {  // B tile NCPx32
            int c = idx >> 2, q = idx & 3;
            *(uint4*)&Bs[c * 40 + q * 8] = *(const uint4*)&Wtg[(size_t)c * K + k0 + q * 8];
        }
        __syncthreads();

        bf16x8 afr[FM], bfr[FN];
#pragma unroll
        for (int fm = 0; fm < FM; ++fm)
            afr[fm] = *(const bf16x8*)&As[(wm0 + fm * 16 + lo) * 40 + 8 * hi];
#pragma unroll
        for (int fn = 0; fn < FN; ++fn)
            bfr[fn] = *(const bf16x8*)&Bs[(wn0 + fn * 16 + lo) * 40 + 8 * hi];
#pragma unroll
        for (int fm = 0; fm < FM; ++fm)
#pragma unroll
            for (int fn = 0; fn < FN; ++fn)
                acc[fm][fn] = __builtin_amdgcn_mfma_f32_16x16x32_bf16(
                    afr[fm], bfr[fn], acc[fm][fn], 0, 0, 0);
    }

#pragma unroll
    for (int fm = 0; fm < FM; ++fm)
#pragma unroll
        for (int fn = 0; fn < FN; ++fn)
#pragma unroll
            for (int r = 0; r < 4; ++r) {
                int row = row0 + wm0 + fm * 16 + hi * 4 + r;
                if (row < M)
                    Cg[(size_t)row * NCP + wn0 + fn * 16 + lo] = f2b(acc[fm][fn][r]);
            }
}

// ---------------------------------------------------------------------------
// Fused 3-branch aggregation, 16B (8 bf16 feats) per lane, 2-edge unroll:
//   z[n,f] = sum_g lrelu(sum_e w_e * sup_g[src_e, f]) / 3
// sup row for branch g: sup + g*gstride + s*rowstride (ushort elements)
// ---------------------------------------------------------------------------
template <int LPN, bool OUT20>
__global__ __launch_bounds__(256) void agg3_kernel(const ushort* __restrict__ sup,
                                                   const int* __restrict__ rowptr,
                                                   const int2* __restrict__ csre,
                                                   float* __restrict__ z, int N, int E,
                                                   int gstride, int rowstride) {
    int t = blockIdx.x * 256 + threadIdx.x;
    int n = t / LPN;
    int sub = t - n * LPN;
    if (n >= N) return;

    float tot[8];
#pragma unroll
    for (int j = 0; j < 8; ++j) tot[j] = 0.f;

#pragma unroll
    for (int g = 0; g < 3; ++g) {
        const int2* ce = csre + (size_t)g * E;
        int beg = rowptr[g * (N + 1) + n];
        int end = rowptr[g * (N + 1) + n + 1];
        const ushort* sg = sup + (size_t)g * gstride + (size_t)sub * 8;
        float a[8];
#pragma unroll
        for (int j = 0; j < 8; ++j) a[j] = 0.f;
        int e = beg;
        for (; e + 1 < end; e += 2) {
            int2 e0 = ce[e];
            int2 e1 = ce[e + 1];
            uint4 v0 = *(const uint4*)&sg[(size_t)e0.x * rowstride];
            uint4 v1 = *(const uint4*)&sg[(size_t)e1.x * rowstride];
            float w0 = __int_as_float(e0.y);
            float w1 = __int_as_float(e1.y);
            a[0] += w0 * blo(v0.x); a[1] += w0 * bhi(v0.x);
            a[2] += w0 * blo(v0.y); a[3] += w0 * bhi(v0.y);
            a[4] += w0 * blo(v0.z); a[5] += w0 * bhi(v0.z);
            a[6] += w0 * blo(v0.w); a[7] += w0 * bhi(v0.w);
            a[0] += w1 * blo(v1.x); a[1] += w1 * bhi(v1.x);
            a[2] += w1 * blo(v1.y); a[3] += w1 * bhi(v1.y);
            a[4] += w1 * blo(v1.z); a[5] += w1 * bhi(v1.z);
            a[6] += w1 * blo(v1.w); a[7] += w1 * bhi(v1.w);
        }
        if (e < end) {
            int2 e0 = ce[e];
            uint4 v0 = *(const uint4*)&sg[(size_t)e0.x * rowstride];
            float w0 = __int_as_float(e0.y);
            a[0] += w0 * blo(v0.x); a[1] += w0 * bhi(v0.x);
            a[2] += w0 * blo(v0.y); a[3] += w0 * bhi(v0.y);
            a[4] += w0 * blo(v0.z); a[5] += w0 * bhi(v0.z);
            a[6] += w0 * blo(v0.w); a[7] += w0 * bhi(v0.w);
        }
#pragma unroll
        for (int j = 0; j < 8; ++j) tot[j] += lrelu(a[j]);
    }

    const float s3 = 1.f / 3.f;
#pragma unroll
    for (int j = 0; j < 8; ++j) tot[j] *= s3;

    if (OUT20) {
        // z rows are 20 floats; lane sub covers feats sub*8..sub*8+7
        int f0 = sub * 8;
        if (f0 < 20) {
            *(float4*)&z[(size_t)n * 20 + f0] =
                make_float4(tot[0], tot[1], tot[2], tot[3]);
            if (f0 + 4 < 20)
                *(float4*)&z[(size_t)n * 20 + f0 + 4] =
                    make_float4(tot[4], tot[5], tot[6], tot[7]);
        }
    } else {
        float* zr = &z[(size_t)n * (8 * LPN) + sub * 8];
        *(float4*)&zr[0] = make_float4(tot[0], tot[1], tot[2], tot[3]);
        *(float4*)&zr[4] = make_float4(tot[4], tot[5], tot[6], tot[7]);
    }
}

// ---------------------------------------------------------------------------
// Student-t soft assignment (V = 1): q = 1/(1+dist), row-normalized
// ---------------------------------------------------------------------------
__global__ void q_kernel(const float* __restrict__ z, const float* __restrict__ cl,
                         float* __restrict__ qout, int N) {
    __shared__ float c[200];
    if (threadIdx.x < 200) c[threadIdx.x] = cl[threadIdx.x];
    __syncthreads();
    int n = blockIdx.x * blockDim.x + threadIdx.x;
    if (n >= N) return;
    float zr[20];
#pragma unroll
    for (int d = 0; d < 20; ++d) zr[d] = z[(size_t)n * 20 + d];
    float qs[10];
    float sum = 0.f;
#pragma unroll
    for (int k = 0; k < 10; ++k) {
        float dist = 0.f;
#pragma unroll
        for (int d = 0; d < 20; ++d) {
            float t = zr[d] - c[k * 20 + d];
            dist += t * t;
        }
        float qk = 1.0f / (1.0f + dist);
        qs[k] = qk;
        sum += qk;
    }
    float inv = 1.0f / sum;
#pragma unroll
    for (int k = 0; k < 10; ++k) qout[(size_t)n * 10 + k] = qs[k] * inv;
}

// ---------------------------------------------------------------------------
extern "C" void kernel_launch(void* const* d_in, const int* in_sizes, int n_in,
                              void* d_out, int out_size, void* d_ws, size_t ws_size,
                              hipStream_t stream) {
    const float* feat[3] = {(const float*)d_in[0], (const float*)d_in[1], (const float*)d_in[2]};
    const int*   srcs[3] = {(const int*)d_in[3], (const int*)d_in[6], (const int*)d_in[9]};
    const int*   dsts[3] = {(const int*)d_in[4], (const int*)d_in[7], (const int*)d_in[10]};
    const float* ews[3]  = {(const float*)d_in[5], (const float*)d_in[8], (const float*)d_in[11]};
    const float* Wp[3][3];
    for (int b = 0; b < 3; ++b)
        for (int l = 0; l < 3; ++l)
            Wp[b][l] = (const float*)d_in[12 + 3 * b + l];
    const float* cluster = (const float*)d_in[21];

    const int N = in_sizes[0] / D_IN;   // 50000
    const int E = in_sizes[3];          // 800000

    // ---- workspace layout ----
    size_t off = 0;
    auto take = [&](size_t bytes) -> void* {
        void* p = (char*)d_ws + off;
        off += (bytes + 255) & ~(size_t)255;
        return p;
    };
    int*    cursor = (int*)take((size_t)3 * N * 4);          // hist -> cursor
    int*    rowptr = (int*)take((size_t)3 * (N + 1) * 4);
    int2*   csre   = (int2*)take((size_t)3 * E * 8);
    ushort* wt1    = (ushort*)take((size_t)3 * 128 * 256 * 2);
    ushort* wt2    = (ushort*)take((size_t)3 * 64 * 128 * 2);
    ushort* wt3    = (ushort*)take((size_t)3 * 32 * 64 * 2);
    ushort* sup    = (ushort*)take((size_t)3 * N * 128 * 2);  // reused per layer
    float*  z1     = (float*)take((size_t)N * 128 * 4);
    float*  z2     = (float*)take((size_t)N * 64 * 4);
    (void)ws_size;

    float* zout = (float*)d_out;                 // [N,20] fp32
    float* qout = zout + (size_t)N * 20;         // [N,10]

    // ---- CSR build ----
    hipMemsetAsync(cursor, 0, (size_t)3 * N * 4, stream);
    int gE = (E + 255) / 256;
    hist3_kernel<<<dim3(gE, 3), 256, 0, stream>>>(dsts[0], dsts[1], dsts[2], cursor, E, N);
    scan3_kernel<<<3, 1024, 0, stream>>>(cursor, rowptr, N);
    scatter3_kernel<<<dim3(gE, 3), 256, 0, stream>>>(srcs[0], srcs[1], srcs[2],
                                                     dsts[0], dsts[1], dsts[2],
                                                     ews[0], ews[1], ews[2],
                                                     cursor, csre, E, N);

    // ---- weight prep (fp32 -> transposed bf16, concatenated) ----
    prep_kernel<256, 128, 128><<<(3 * 128 * 256 + 255) / 256, 256, 0, stream>>>(
        Wp[0][0], Wp[1][0], Wp[2][0], wt1);
    prep_kernel<128, 64, 64><<<(3 * 64 * 128 + 255) / 256, 256, 0, stream>>>(
        Wp[0][1], Wp[1][1], Wp[2][1], wt2);
    prep_kernel<64, 20, 32><<<(3 * 32 * 64 + 255) / 256, 256, 0, stream>>>(
        Wp[0][2], Wp[1][2], Wp[2][2], wt3);

    int gM = (N + 127) / 128;   // 391

    // ---- layer 1: per-branch [N,256]@[256,128], batched over branches ----
    gemm_kernel<256, 128, true><<<dim3(gM, 3), 256, 0, stream>>>(
        feat[0], feat[1], feat[2], wt1, sup, N);
    agg3_kernel<16, false><<<(N * 16 + 255) / 256, 256, 0, stream>>>(
        sup, rowptr, csre, z1, N, E, N * 128, 128);

    // ---- layer 2: fused [N,128]@[128,192] (3 branches concatenated) ----
    gemm_kernel<128, 192, false><<<gM, 256, 0, stream>>>(z1, z1, z1, wt2, sup, N);
    agg3_kernel<8, false><<<(N * 8 + 255) / 256, 256, 0, stream>>>(
        sup, rowptr, csre, z2, N, E, 64, 192);

    // ---- layer 3: fused [N,64]@[64,96] -> agg -> zout fp32 ----
    gemm_kernel<64, 96, false><<<gM, 256, 0, stream>>>(z2, z2, z2, wt3, sup, N);
    agg3_kernel<4, true><<<(N * 4 + 255) / 256, 256, 0, stream>>>(
        sup, rowptr, csre, zout, N, E, 32, 96);

    // ---- student-t q ----
    q_kernel<<<(N + 255) / 256, 256, 0, stream>>>(zout, cluster, qout, N);
}